// Round 6
// baseline (694.794 us; speedup 1.0000x reference)
//
#include <hip/hip_runtime.h>

#define DFEAT 256
#define NEG_ATT 0.2f
#define NEG_ACT 0.01f
#define BN_EPS 1e-5f

typedef short bf16x8 __attribute__((ext_vector_type(8)));
typedef float f32x4 __attribute__((ext_vector_type(4)));

struct Int3 { int a[3]; };
struct Cp3 { const void* p[3]; };
struct Vp3 { void* p[3]; };

__device__ __forceinline__ float lrelu(float x, float s) { return x > 0.f ? x : s * x; }

__device__ __forceinline__ unsigned short f2bf(float f) {
    union { float f; unsigned int u; } v; v.f = f;
    unsigned int u = v.u;
    unsigned int r = (u + 0x7FFFu + ((u >> 16) & 1u)) >> 16;   // RNE
    return (unsigned short)r;
}
__device__ __forceinline__ float bf2f(unsigned short s) {
    union { unsigned int u; float f; } v; v.u = ((unsigned int)s) << 16;
    return v.f;
}
__device__ __forceinline__ float u_lo(unsigned u) {
    union { unsigned u; float f; } v; v.u = u << 16; return v.f;
}
__device__ __forceinline__ float u_hi(unsigned u) {
    union { unsigned u; float f; } v; v.u = u & 0xffff0000u; return v.f;
}

// ---------------- histogram of dst (all types) ----------------
__global__ __launch_bounds__(256)
void hist_all_k(Cp3 dst, Int3 E, int* __restrict__ counts_all, Int3 nodeOff) {
    int t = blockIdx.y;
    int e = blockIdx.x * 256 + threadIdx.x;
    if (e >= E.a[t]) return;
    const int* dstp = (const int*)dst.p[t];
    atomicAdd(&counts_all[nodeOff.a[t] + dstp[e]], 1);
}

// ---------------- hierarchical exclusive scan (all types) ----------------
__global__ __launch_bounds__(256)
void scan1_all_k(const int* __restrict__ counts_all, int* __restrict__ offs_all,
                 int* __restrict__ bsums_all, Int3 N, Int3 nodeOff, Int3 bOff) {
    int t = blockIdx.y;
    if (blockIdx.x * 256 >= N.a[t]) return;
    const int* counts = counts_all + nodeOff.a[t];
    int* offs = offs_all + nodeOff.a[t] + t;
    int* bsums = bsums_all + bOff.a[t];
    __shared__ int buf[256];
    int tt = threadIdx.x;
    int i = blockIdx.x * 256 + tt;
    int v = (i < N.a[t]) ? counts[i] : 0;
    buf[tt] = v;
    __syncthreads();
    for (int off = 1; off < 256; off <<= 1) {
        int x = (tt >= off) ? buf[tt - off] : 0;
        __syncthreads();
        buf[tt] += x;
        __syncthreads();
    }
    if (i < N.a[t]) offs[i] = buf[tt];            // inclusive within block
    if (tt == 255) bsums[blockIdx.x] = buf[255];
}

__global__ __launch_bounds__(256)
void scan2_all_k(int* __restrict__ bsums_all, Int3 N, Int3 bOff) {
    int t = blockIdx.x;
    int nb = (N.a[t] + 255) / 256;
    int* bsums = bsums_all + bOff.a[t];
    __shared__ int buf[256];
    __shared__ int carry_s;
    int tt = threadIdx.x;
    if (tt == 0) carry_s = 0;
    __syncthreads();
    for (int base = 0; base < nb; base += 256) {
        int i = base + tt;
        int v = (i < nb) ? bsums[i] : 0;
        buf[tt] = v;
        __syncthreads();
        for (int off = 1; off < 256; off <<= 1) {
            int x = (tt >= off) ? buf[tt - off] : 0;
            __syncthreads();
            buf[tt] += x;
            __syncthreads();
        }
        int incl = buf[tt];
        int c = carry_s;
        if (i < nb) bsums[i] = c + incl - v;
        __syncthreads();
        if (tt == 255) carry_s = c + buf[255];
        __syncthreads();
    }
}

__global__ __launch_bounds__(256)
void scan3_all_k(int* __restrict__ offs_all, const int* __restrict__ counts_all,
                 const int* __restrict__ bsums_all, Int3 N, Int3 E,
                 Int3 nodeOff, Int3 bOff) {
    int t = blockIdx.y;
    if (blockIdx.x * 256 >= N.a[t]) return;
    int* offs = offs_all + nodeOff.a[t] + t;
    const int* counts = counts_all + nodeOff.a[t];
    const int* bsums = bsums_all + bOff.a[t];
    int i = blockIdx.x * 256 + threadIdx.x;
    if (i < N.a[t]) offs[i] = offs[i] - counts[i] + bsums[blockIdx.x];
    if (i == 0) offs[N.a[t]] = E.a[t];
}

// ---------------- scatter edges into CSR (atomicSub restores counts to 0) ----------------
__global__ __launch_bounds__(256)
void scatter_all_k(Cp3 src, Cp3 dst, Int3 E, const int* __restrict__ offs_all,
                   int* __restrict__ counts_all, int* __restrict__ csr_all,
                   Int3 nodeOff, Int3 edgeOff) {
    int t = blockIdx.y;
    int e = blockIdx.x * 256 + threadIdx.x;
    if (e >= E.a[t]) return;
    const int* srcp = (const int*)src.p[t];
    const int* dstp = (const int*)dst.p[t];
    const int* offs = offs_all + nodeOff.a[t] + t;
    int* cursor = counts_all + nodeOff.a[t];
    int* csr = csr_all + edgeOff.a[t];
    int d = dstp[e];
    int pos = atomicSub(&cursor[d], 1) - 1;   // counts end back at 0
    csr[offs[d] + pos] = srcp[e];
}

// ---------------- all weight transposes (bf16) in one dispatch ----------------
__global__ __launch_bounds__(256)
void wcast_all_k(const float* __restrict__ Wl1, const float* __restrict__ Wr1,
                 const float* __restrict__ Wl2, const float* __restrict__ Wr2,
                 unsigned short* __restrict__ Bt1, unsigned short* __restrict__ Bt2) {
    int idx = blockIdx.x * 256 + threadIdx.x;
    const int S1 = 3 * 512 * 128;
    const int S2 = 3 * 512 * 256;
    if (idx < S1) {
        int ty = idx / (512 * 128);
        int r = idx - ty * (512 * 128);
        int n = r >> 7, k = r & 127;
        const float* W = ((n < 256) ? Wl1 : Wr1) + (size_t)ty * 128 * 256;
        Bt1[idx] = f2bf(W[(size_t)k * 256 + (n & 255)]);
    } else if (idx < S1 + S2) {
        int r2 = idx - S1;
        int ty = r2 / (512 * 256);
        int r = r2 - ty * (512 * 256);
        int n = r >> 8, k = r & 255;
        const float* W = ((n < 256) ? Wl2 : Wr2) + (size_t)ty * 256 * 256;
        Bt2[r2] = f2bf(W[(size_t)k * 256 + (n & 255)]);
    }
}

// ---------------- MFMA GEMM (all types): C[M,512] bf16 = A[M,K] @ Bt[512,K]^T ----------------
template<int AF32>
__global__ __launch_bounds__(256)
void mfma_gemm_all_k(Cp3 Ap3, Cp3 Bp3, Vp3 Cp3v, Int3 M3, int K) {
    int t = blockIdx.z;
    int M = M3.a[t];
    int bm = blockIdx.x * 128;
    if (bm >= M) return;
    const void* Ap = Ap3.p[t];
    const unsigned short* Bt = (const unsigned short*)Bp3.p[t];
    unsigned short* C = (unsigned short*)Cp3v.p[t];
    const int LDK = 40;                       // padded LDS row stride
    __shared__ unsigned short As[128 * LDK];
    __shared__ unsigned short Bs[128 * LDK];
    int tid = threadIdx.x;
    int bn = blockIdx.y * 128;
    int wid = tid >> 6, lane = tid & 63;
    int quad = lane >> 4, l16 = lane & 15;
    int mw = (wid & 1) * 64, nw = (wid >> 1) * 64;
    f32x4 acc[4][4] = {};
    for (int k0 = 0; k0 < K; k0 += 32) {
#pragma unroll
        for (int i = 0; i < 2; ++i) {
            int c = tid + 256 * i;            // 0..511
            int row = c >> 2, ko = (c & 3) * 8;
            int ra = bm + row; if (ra >= M) ra = M - 1;
            if (AF32) {
                const float* Af = (const float*)Ap;
                float4 a0 = *(const float4*)(Af + (size_t)ra * K + k0 + ko);
                float4 a1 = *(const float4*)(Af + (size_t)ra * K + k0 + ko + 4);
                ushort4 lo, hi;
                lo.x = f2bf(a0.x); lo.y = f2bf(a0.y); lo.z = f2bf(a0.z); lo.w = f2bf(a0.w);
                hi.x = f2bf(a1.x); hi.y = f2bf(a1.y); hi.z = f2bf(a1.z); hi.w = f2bf(a1.w);
                *(ushort4*)&As[row * LDK + ko] = lo;
                *(ushort4*)&As[row * LDK + ko + 4] = hi;
            } else {
                const unsigned short* Ab = (const unsigned short*)Ap;
                uint4 va = *(const uint4*)(Ab + (size_t)ra * K + k0 + ko);
                *(uint4*)&As[row * LDK + ko] = va;
            }
            uint4 vb = *(const uint4*)(Bt + (size_t)(bn + row) * K + k0 + ko);
            *(uint4*)&Bs[row * LDK + ko] = vb;
        }
        __syncthreads();
        bf16x8 af[4], bfv[4];
#pragma unroll
        for (int i = 0; i < 4; ++i)
            af[i] = *(bf16x8*)&As[(mw + 16 * i + l16) * LDK + quad * 8];
#pragma unroll
        for (int u = 0; u < 4; ++u)
            bfv[u] = *(bf16x8*)&Bs[(nw + 16 * u + l16) * LDK + quad * 8];
#pragma unroll
        for (int i = 0; i < 4; ++i)
#pragma unroll
            for (int u = 0; u < 4; ++u)
                acc[i][u] = __builtin_amdgcn_mfma_f32_16x16x32_bf16(af[i], bfv[u], acc[i][u], 0, 0, 0);
        __syncthreads();
    }
#pragma unroll
    for (int i = 0; i < 4; ++i) {
#pragma unroll
        for (int r = 0; r < 4; ++r) {
            int grow = bm + mw + 16 * i + quad * 4 + r;
            if (grow < M) {
#pragma unroll
                for (int u = 0; u < 4; ++u) {
                    int gcol = bn + nw + 16 * u + l16;
                    C[(size_t)grow * 512 + gcol] = f2bf(acc[i][u][r]);
                }
            }
        }
    }
}

// ---------------- GATv2 gather (all types): quad-parallel edges ----------------
// Each 16-lane quad processes a different edge; lane owns 16 contiguous channels
// (l16*16..+15, all within head l16/4). Score reduce = shfl_xor 1,2 within
// 4-lane clusters (quad-local). Cross-quad combine once per node at the end.
__global__ __launch_bounds__(256)
void gat_gather_all_k(Cp3 hl3, Cp3 offs3, Cp3 csr3, Cp3 att3, Cp3 bias3,
                      Vp3 out3, Int3 N3) {
    int t = blockIdx.z;
    int N = N3.a[t];
    int wave = (blockIdx.x * 256 + threadIdx.x) >> 6;
    int lane = threadIdx.x & 63;
    if (wave >= N) return;
    int d = wave;
    int quad = lane >> 4, l16 = lane & 15;
    const char* hlB = (const char*)hl3.p[t];       // row stride 1024 B (hl||hr)
    const int* offs = (const int*)offs3.p[t];
    const int* csr = (const int*)csr3.p[t];
    const float* att = (const float*)att3.p[t];
    const float* bias = (const float*)bias3.p[t];
    unsigned short* out = (unsigned short*)out3.p[t];

    unsigned fOff = (unsigned)(l16 << 5);          // 32 B of bf16 = 16 channels

    float hrf[16], attf[16], ac[16];
    {
        unsigned off = ((unsigned)d << 10) + 512u + fOff;   // hr part of row d
        uint4 u0 = *(const uint4*)(hlB + off);
        uint4 u1 = *(const uint4*)(hlB + off + 16);
        const unsigned* up0 = (const unsigned*)&u0;
        const unsigned* up1 = (const unsigned*)&u1;
#pragma unroll
        for (int j = 0; j < 4; ++j) {
            hrf[2 * j] = u_lo(up0[j]);     hrf[2 * j + 1] = u_hi(up0[j]);
            hrf[8 + 2 * j] = u_lo(up1[j]); hrf[8 + 2 * j + 1] = u_hi(up1[j]);
        }
        const float4* ap4 = (const float4*)(att + (l16 << 4));
#pragma unroll
        for (int j = 0; j < 4; ++j) {
            float4 v = ap4[j];
            attf[4 * j] = v.x; attf[4 * j + 1] = v.y;
            attf[4 * j + 2] = v.z; attf[4 * j + 3] = v.w;
        }
    }
#pragma unroll
    for (int j = 0; j < 16; ++j) ac[j] = 0.f;
    float lsum = 0.f;

    auto edge_update = [&](int s, bool active) {
        unsigned off = ((unsigned)s << 10) + fOff;
        uint4 u0 = *(const uint4*)(hlB + off);
        uint4 u1 = *(const uint4*)(hlB + off + 16);
        const unsigned* up0 = (const unsigned*)&u0;
        const unsigned* up1 = (const unsigned*)&u1;
        float h[16];
#pragma unroll
        for (int j = 0; j < 4; ++j) {
            h[2 * j] = u_lo(up0[j]);     h[2 * j + 1] = u_hi(up0[j]);
            h[8 + 2 * j] = u_lo(up1[j]); h[8 + 2 * j + 1] = u_hi(up1[j]);
        }
        float part = 0.f;
#pragma unroll
        for (int j = 0; j < 16; ++j) {
            float x = h[j] + hrf[j];
            x = fmaxf(x, NEG_ATT * x);      // exact leaky_relu for slope<1
            part = fmaf(x, attf[j], part);
        }
        part += __shfl_xor(part, 1);
        part += __shfl_xor(part, 2);        // 4-lane cluster = one head
        float p = active ? __expf(part) : 0.f;   // scores small: shift-free softmax safe
        lsum += p;
#pragma unroll
        for (int j = 0; j < 16; ++j) ac[j] = fmaf(p, h[j], ac[j]);
    };

    if (quad == 0) edge_update(d, true);            // self-loop (quad-local shfls safe)

    int beg = offs[d];
    int deg = offs[d + 1] - beg;
    for (int base = 0; base < deg; base += 64) {
        int cnt = min(64, deg - base);
        int my = (base + lane < deg) ? csr[beg + base + lane] : d;
#pragma unroll 4
        for (int g = 0; g < cnt; g += 4) {
            int vi = g + quad;
            int s = __shfl(my, vi);
            edge_update(s, vi < cnt);
        }
    }

    // cross-quad combine (once per node)
    lsum += __shfl_xor(lsum, 16);
    lsum += __shfl_xor(lsum, 32);
#pragma unroll
    for (int j = 0; j < 16; ++j) {
        ac[j] += __shfl_xor(ac[j], 16);
        ac[j] += __shfl_xor(ac[j], 32);
    }

    if (quad == 0) {
        float inv = 1.f / (lsum + 1e-16f);
        const float* bp = bias + (l16 << 4);
        unsigned o[8];
#pragma unroll
        for (int j = 0; j < 8; ++j) {
            float v0 = ac[2 * j] * inv + bp[2 * j];
            float v1 = ac[2 * j + 1] * inv + bp[2 * j + 1];
            o[j] = (unsigned)f2bf(v0) | ((unsigned)f2bf(v1) << 16);
        }
        unsigned short* op = out + ((size_t)d << 8) + (l16 << 4);
        *(uint4*)op = make_uint4(o[0], o[1], o[2], o[3]);
        *(uint4*)(op + 8) = make_uint4(o[4], o[5], o[6], o[7]);
    }
}

// ---------------- BN stats (all types): vectorized ushort8 loads ----------------
__global__ __launch_bounds__(256)
void bn_stats_all_k(Cp3 h3, Vp3 st3, Int3 N3) {
    int t = blockIdx.y;
    const unsigned short* hp = (const unsigned short*)h3.p[t];
    float* st = (float*)st3.p[t];
    long total = (long)N3.a[t] * 256;
    int tid = threadIdx.x;
    long gt = (long)blockIdx.x * 256 + tid;
    long stride = (long)gridDim.x * 256 * 8;
    float s[8] = {0.f}, s2[8] = {0.f};
    for (long p = gt * 8; p < total; p += stride) {
        uint4 u = *(const uint4*)(hp + p);
        unsigned short* us = (unsigned short*)&u;   // 8 bf16
#pragma unroll
        for (int j = 0; j < 8; ++j) { float v = bf2f(us[j]); s[j] += v; s2[j] += v * v; }
    }
#pragma unroll
    for (int j = 0; j < 8; ++j) { s[j] += __shfl_xor(s[j], 32); s2[j] += __shfl_xor(s2[j], 32); }
    __shared__ float lds[2048];
    int wv = tid >> 6, lane = tid & 63;
    if (lane < 32) {
#pragma unroll
        for (int j = 0; j < 8; ++j) {
            lds[wv * 512 + lane * 8 + j] = s[j];
            lds[wv * 512 + 256 + lane * 8 + j] = s2[j];
        }
    }
    __syncthreads();
    for (int q = tid; q < 512; q += 256) {
        float v = lds[q] + lds[512 + q] + lds[1024 + q] + lds[1536 + q];
        atomicAdd(&st[q], v);
    }
}

// ---------------- BN apply + leaky_relu (all types), in-place bf16 ----------------
__global__ __launch_bounds__(256)
void bn_apply_all_k(Vp3 h3, Cp3 st3, const float* __restrict__ gb, const float* __restrict__ bb,
                    Int3 N3) {
    int t = blockIdx.y;
    int N = N3.a[t];
    size_t idx = (size_t)blockIdx.x * 256 + threadIdx.x;   // ushort4 index
    if (idx >= (size_t)N * 64) return;
    unsigned short* h = (unsigned short*)h3.p[t];
    const float* stats = (const float*)st3.p[t];
    const float* g = gb + (size_t)t * DFEAT;
    const float* b = bb + (size_t)t * DFEAT;
    int f4 = ((int)(idx & 63)) << 2;
    float invN = 1.f / (float)N;
    ushort4 u = ((const ushort4*)h)[idx];
    float vv[4] = {bf2f(u.x), bf2f(u.y), bf2f(u.z), bf2f(u.w)};
    ushort4 ov;
    unsigned short* op = (unsigned short*)&ov;
#pragma unroll
    for (int j = 0; j < 4; ++j) {
        int f = f4 + j;
        float mu  = stats[f] * invN;
        float var = stats[DFEAT + f] * invN - mu * mu;
        float sc  = g[f] / sqrtf(var + BN_EPS);
        float val = (vv[j] - mu) * sc + b[f];
        op[j] = f2bf(lrelu(val, NEG_ACT));
    }
    ((ushort4*)h)[idx] = ov;
}

// ---------------- fused BN + leaky_relu + classifier (all types) ----------------
__global__ __launch_bounds__(256)
void bn_cls_all_k(Cp3 R3, Cp3 st3, const float* __restrict__ gb, const float* __restrict__ bb,
                  const float* __restrict__ cW, const float* __restrict__ cb,
                  Vp3 out3, Int3 N3) {
    int t = blockIdx.y;
    int N = N3.a[t];
    int wave = (blockIdx.x * 256 + threadIdx.x) >> 6;
    int lane = threadIdx.x & 63;
    if (wave >= N) return;
    const unsigned short* R = (const unsigned short*)R3.p[t];
    const float* stats = (const float*)st3.p[t];
    const float* g = gb + (size_t)t * DFEAT;
    const float* b = bb + (size_t)t * DFEAT;
    float* out = (float*)out3.p[t];
    int f4 = lane << 2;
    float invN = 1.f / (float)N;
    ushort4 u = *(const ushort4*)(R + (size_t)wave * DFEAT + f4);
    float vv[4] = {bf2f(u.x), bf2f(u.y), bf2f(u.z), bf2f(u.w)};
    float p0 = 0.f, p1 = 0.f;
#pragma unroll
    for (int j = 0; j < 4; ++j) {
        int f = f4 + j;
        float mu  = stats[f] * invN;
        float var = stats[DFEAT + f] * invN - mu * mu;
        float sc  = g[f] / sqrtf(var + BN_EPS);
        float val = lrelu((vv[j] - mu) * sc + b[f], NEG_ACT);
        float2 w = *(const float2*)(cW + (size_t)f * 2);
        p0 += val * w.x;
        p1 += val * w.y;
    }
#pragma unroll
    for (int off = 1; off < 64; off <<= 1) {
        p0 += __shfl_xor(p0, off);
        p1 += __shfl_xor(p1, off);
    }
    if (lane == 0) {
        out[(size_t)wave * 2 + 0] = p0 + cb[0];
        out[(size_t)wave * 2 + 1] = p1 + cb[1];
    }
}

extern "C" void kernel_launch(void* const* d_in, const int* in_sizes, int n_in,
                              void* d_out, int out_size, void* d_ws, size_t ws_size,
                              hipStream_t stream) {
    const float* x0 = (const float*)d_in[0];
    const float* x1 = (const float*)d_in[1];
    const float* x2 = (const float*)d_in[2];
    const int* ei[3] = {(const int*)d_in[3], (const int*)d_in[4], (const int*)d_in[5]};
    const float* Wl1 = (const float*)d_in[6];
    const float* Wr1 = (const float*)d_in[7];
    const float* att1 = (const float*)d_in[8];
    const float* b1 = (const float*)d_in[9];
    const float* Wl2 = (const float*)d_in[10];
    const float* Wr2 = (const float*)d_in[11];
    const float* att2 = (const float*)d_in[12];
    const float* b2 = (const float*)d_in[13];
    const float* bn_g = (const float*)d_in[14];
    const float* bn_b = (const float*)d_in[15];
    const float* cW = (const float*)d_in[16];
    const float* cb = (const float*)d_in[17];

    Int3 N3, E3, nodeOff, edgeOff, bOff;
    N3.a[0] = in_sizes[0] / 128; N3.a[1] = in_sizes[1] / 128; N3.a[2] = in_sizes[2] / 128;
    E3.a[0] = in_sizes[3] / 2;   E3.a[1] = in_sizes[4] / 2;   E3.a[2] = in_sizes[5] / 2;
    int Ntot = 0, Etot = 0, btot = 0;
    int maxN = 0, maxE = 0;
    for (int i = 0; i < 3; ++i) {
        nodeOff.a[i] = Ntot; edgeOff.a[i] = Etot; bOff.a[i] = btot;
        Ntot += N3.a[i]; Etot += E3.a[i]; btot += (N3.a[i] + 255) / 256;
        if (N3.a[i] > maxN) maxN = N3.a[i];
        if (E3.a[i] > maxE) maxE = E3.a[i];
    }

    char* w = (char*)d_ws;
    auto alloc_b = [&](size_t bytes) -> void* {
        void* p = (void*)w;
        w += (bytes + 255) & ~(size_t)255;
        return p;
    };
    unsigned short* C_all  = (unsigned short*)alloc_b((size_t)Ntot * 512 * sizeof(unsigned short));
    unsigned short* Rb_all = (unsigned short*)alloc_b((size_t)Ntot * DFEAT * sizeof(unsigned short));
    unsigned short* Bt1 = (unsigned short*)alloc_b((size_t)3 * 512 * 128 * sizeof(unsigned short));
    unsigned short* Bt2 = (unsigned short*)alloc_b((size_t)3 * 512 * 256 * sizeof(unsigned short));
    int* counts_all = (int*)alloc_b((size_t)Ntot * sizeof(int));
    int* offs_all   = (int*)alloc_b((size_t)(Ntot + 3) * sizeof(int));
    int* csr_all    = (int*)alloc_b((size_t)Etot * sizeof(int));
    int* bsums_all  = (int*)alloc_b((size_t)btot * sizeof(int));
    float* stats_all = (float*)alloc_b((size_t)6 * 512 * sizeof(float));

    // per-type pointer packs
    Cp3 srcP, dstP, xP, Bt1P, Bt2P, hlP, offsP, csrP, att1P, att2P, b1P, b2P;
    Cp3 RbCP, st1CP, st2CP;
    Vp3 CP, RbP, st1P, st2P, outP;
    for (int i = 0; i < 3; ++i) {
        srcP.p[i] = ei[i];
        dstP.p[i] = ei[i] + E3.a[i];
        xP.p[i] = (i == 0) ? (const void*)x0 : (i == 1) ? (const void*)x1 : (const void*)x2;
        Bt1P.p[i] = Bt1 + (size_t)i * 512 * 128;
        Bt2P.p[i] = Bt2 + (size_t)i * 512 * 256;
        CP.p[i] = C_all + (size_t)nodeOff.a[i] * 512;
        hlP.p[i] = CP.p[i];
        RbP.p[i] = Rb_all + (size_t)nodeOff.a[i] * DFEAT;
        RbCP.p[i] = RbP.p[i];
        offsP.p[i] = offs_all + nodeOff.a[i] + i;
        csrP.p[i] = csr_all + edgeOff.a[i];
        att1P.p[i] = att1 + (size_t)i * DFEAT;
        att2P.p[i] = att2 + (size_t)i * DFEAT;
        b1P.p[i] = b1 + (size_t)i * DFEAT;
        b2P.p[i] = b2 + (size_t)i * DFEAT;
        st1P.p[i] = stats_all + (size_t)i * 512;
        st2P.p[i] = stats_all + (size_t)(3 + i) * 512;
        st1CP.p[i] = st1P.p[i];
        st2CP.p[i] = st2P.p[i];
        outP.p[i] = (float*)d_out + (size_t)nodeOff.a[i] * 2;
    }

    int maxNblk = (maxN + 255) / 256;
    int maxEblk = (maxE + 255) / 256;
    int maxMtile = (maxN + 127) / 128;
    int maxNwave = (maxN + 3) / 4;

    // one-time prep
    hipMemsetAsync(counts_all, 0, (size_t)Ntot * sizeof(int), stream);
    hipMemsetAsync(stats_all, 0, (size_t)6 * 512 * sizeof(float), stream);
    {
        int tot = 3 * 512 * 128 + 3 * 512 * 256;
        wcast_all_k<<<(tot + 255) / 256, 256, 0, stream>>>(Wl1, Wr1, Wl2, Wr2, Bt1, Bt2);
    }

    // ---- CSR build (all types) ----
    hist_all_k<<<dim3(maxEblk, 3), 256, 0, stream>>>(dstP, E3, counts_all, nodeOff);
    scan1_all_k<<<dim3(maxNblk, 3), 256, 0, stream>>>(counts_all, offs_all, bsums_all, N3, nodeOff, bOff);
    scan2_all_k<<<3, 256, 0, stream>>>(bsums_all, N3, bOff);
    scan3_all_k<<<dim3(maxNblk, 3), 256, 0, stream>>>(offs_all, counts_all, bsums_all, N3, E3, nodeOff, bOff);
    scatter_all_k<<<dim3(maxEblk, 3), 256, 0, stream>>>(srcP, dstP, E3, offs_all, counts_all, csr_all, nodeOff, edgeOff);

    // ---- layer 1 ----
    mfma_gemm_all_k<1><<<dim3(maxMtile, 4, 3), 256, 0, stream>>>(xP, Bt1P, CP, N3, 128);
    gat_gather_all_k<<<dim3(maxNwave, 1, 3), 256, 0, stream>>>(hlP, offsP, csrP, att1P, b1P, RbP, N3);
    bn_stats_all_k<<<dim3(512, 3), 256, 0, stream>>>(RbCP, st1P, N3);
    bn_apply_all_k<<<dim3(maxNwave, 3), 256, 0, stream>>>(RbP, st1CP, bn_g, bn_b, N3);

    // ---- layer 2 (A = Rb bf16, in-place BN output) ----
    mfma_gemm_all_k<0><<<dim3(maxMtile, 4, 3), 256, 0, stream>>>(RbCP, Bt2P, CP, N3, 256);
    gat_gather_all_k<<<dim3(maxNwave, 1, 3), 256, 0, stream>>>(hlP, offsP, csrP, att2P, b2P, RbP, N3);
    bn_stats_all_k<<<dim3(512, 3), 256, 0, stream>>>(RbCP, st2P, N3);

    // ---- fused BN + lrelu + classifier ----
    bn_cls_all_k<<<dim3(maxNwave, 3), 256, 0, stream>>>(RbCP, st2CP, bn_g, bn_b, cW, cb, outP, N3);
}

// Round 7
// 576.793 us; speedup vs baseline: 1.2046x; 1.2046x over previous
//
#include <hip/hip_runtime.h>

#define DFEAT 256
#define NEG_ATT 0.2f
#define NEG_ACT 0.01f
#define BN_EPS 1e-5f

typedef short bf16x8 __attribute__((ext_vector_type(8)));
typedef float f32x4 __attribute__((ext_vector_type(4)));

struct Int3 { int a[3]; };
struct Cp3 { const void* p[3]; };
struct Vp3 { void* p[3]; };

__device__ __forceinline__ float lrelu(float x, float s) { return x > 0.f ? x : s * x; }

__device__ __forceinline__ unsigned short f2bf(float f) {
    union { float f; unsigned int u; } v; v.f = f;
    unsigned int u = v.u;
    unsigned int r = (u + 0x7FFFu + ((u >> 16) & 1u)) >> 16;   // RNE
    return (unsigned short)r;
}
__device__ __forceinline__ float bf2f(unsigned short s) {
    union { unsigned int u; float f; } v; v.u = ((unsigned int)s) << 16;
    return v.f;
}

// ---------------- histogram of dst (all types) ----------------
__global__ __launch_bounds__(256)
void hist_all_k(Cp3 dst, Int3 E, int* __restrict__ counts_all, Int3 nodeOff) {
    int t = blockIdx.y;
    int e = blockIdx.x * 256 + threadIdx.x;
    if (e >= E.a[t]) return;
    const int* dstp = (const int*)dst.p[t];
    atomicAdd(&counts_all[nodeOff.a[t] + dstp[e]], 1);
}

// ---------------- hierarchical exclusive scan (all types) ----------------
__global__ __launch_bounds__(256)
void scan1_all_k(const int* __restrict__ counts_all, int* __restrict__ offs_all,
                 int* __restrict__ bsums_all, Int3 N, Int3 nodeOff, Int3 bOff) {
    int t = blockIdx.y;
    if (blockIdx.x * 256 >= N.a[t]) return;
    const int* counts = counts_all + nodeOff.a[t];
    int* offs = offs_all + nodeOff.a[t] + t;
    int* bsums = bsums_all + bOff.a[t];
    __shared__ int buf[256];
    int tt = threadIdx.x;
    int i = blockIdx.x * 256 + tt;
    int v = (i < N.a[t]) ? counts[i] : 0;
    buf[tt] = v;
    __syncthreads();
    for (int off = 1; off < 256; off <<= 1) {
        int x = (tt >= off) ? buf[tt - off] : 0;
        __syncthreads();
        buf[tt] += x;
        __syncthreads();
    }
    if (i < N.a[t]) offs[i] = buf[tt];            // inclusive within block
    if (tt == 255) bsums[blockIdx.x] = buf[255];
}

__global__ __launch_bounds__(256)
void scan2_all_k(int* __restrict__ bsums_all, Int3 N, Int3 bOff) {
    int t = blockIdx.x;
    int nb = (N.a[t] + 255) / 256;
    int* bsums = bsums_all + bOff.a[t];
    __shared__ int buf[256];
    __shared__ int carry_s;
    int tt = threadIdx.x;
    if (tt == 0) carry_s = 0;
    __syncthreads();
    for (int base = 0; base < nb; base += 256) {
        int i = base + tt;
        int v = (i < nb) ? bsums[i] : 0;
        buf[tt] = v;
        __syncthreads();
        for (int off = 1; off < 256; off <<= 1) {
            int x = (tt >= off) ? buf[tt - off] : 0;
            __syncthreads();
            buf[tt] += x;
            __syncthreads();
        }
        int incl = buf[tt];
        int c = carry_s;
        if (i < nb) bsums[i] = c + incl - v;
        __syncthreads();
        if (tt == 255) carry_s = c + buf[255];
        __syncthreads();
    }
}

__global__ __launch_bounds__(256)
void scan3_all_k(int* __restrict__ offs_all, const int* __restrict__ counts_all,
                 const int* __restrict__ bsums_all, Int3 N, Int3 E,
                 Int3 nodeOff, Int3 bOff) {
    int t = blockIdx.y;
    if (blockIdx.x * 256 >= N.a[t]) return;
    int* offs = offs_all + nodeOff.a[t] + t;
    const int* counts = counts_all + nodeOff.a[t];
    const int* bsums = bsums_all + bOff.a[t];
    int i = blockIdx.x * 256 + threadIdx.x;
    if (i < N.a[t]) offs[i] = offs[i] - counts[i] + bsums[blockIdx.x];
    if (i == 0) offs[N.a[t]] = E.a[t];
}

// ---------------- scatter edges into CSR (atomicSub restores counts to 0) ----------------
__global__ __launch_bounds__(256)
void scatter_all_k(Cp3 src, Cp3 dst, Int3 E, const int* __restrict__ offs_all,
                   int* __restrict__ counts_all, int* __restrict__ csr_all,
                   Int3 nodeOff, Int3 edgeOff) {
    int t = blockIdx.y;
    int e = blockIdx.x * 256 + threadIdx.x;
    if (e >= E.a[t]) return;
    const int* srcp = (const int*)src.p[t];
    const int* dstp = (const int*)dst.p[t];
    const int* offs = offs_all + nodeOff.a[t] + t;
    int* cursor = counts_all + nodeOff.a[t];
    int* csr = csr_all + edgeOff.a[t];
    int d = dstp[e];
    int pos = atomicSub(&cursor[d], 1) - 1;   // counts end back at 0
    csr[offs[d] + pos] = srcp[e];
}

// ---------------- all weight transposes (bf16) in one dispatch ----------------
__global__ __launch_bounds__(256)
void wcast_all_k(const float* __restrict__ Wl1, const float* __restrict__ Wr1,
                 const float* __restrict__ Wl2, const float* __restrict__ Wr2,
                 unsigned short* __restrict__ Bt1, unsigned short* __restrict__ Bt2) {
    int idx = blockIdx.x * 256 + threadIdx.x;
    const int S1 = 3 * 512 * 128;
    const int S2 = 3 * 512 * 256;
    if (idx < S1) {
        int ty = idx / (512 * 128);
        int r = idx - ty * (512 * 128);
        int n = r >> 7, k = r & 127;
        const float* W = ((n < 256) ? Wl1 : Wr1) + (size_t)ty * 128 * 256;
        Bt1[idx] = f2bf(W[(size_t)k * 256 + (n & 255)]);
    } else if (idx < S1 + S2) {
        int r2 = idx - S1;
        int ty = r2 / (512 * 256);
        int r = r2 - ty * (512 * 256);
        int n = r >> 8, k = r & 255;
        const float* W = ((n < 256) ? Wl2 : Wr2) + (size_t)ty * 256 * 256;
        Bt2[r2] = f2bf(W[(size_t)k * 256 + (n & 255)]);
    }
}

// ---------------- MFMA GEMM (all types): C[M,512] bf16 = A[M,K] @ Bt[512,K]^T ----------------
template<int AF32>
__global__ __launch_bounds__(256)
void mfma_gemm_all_k(Cp3 Ap3, Cp3 Bp3, Vp3 Cp3v, Int3 M3, int K) {
    int t = blockIdx.z;
    int M = M3.a[t];
    int bm = blockIdx.x * 128;
    if (bm >= M) return;
    const void* Ap = Ap3.p[t];
    const unsigned short* Bt = (const unsigned short*)Bp3.p[t];
    unsigned short* C = (unsigned short*)Cp3v.p[t];
    const int LDK = 40;                       // padded LDS row stride
    __shared__ unsigned short As[128 * LDK];
    __shared__ unsigned short Bs[128 * LDK];
    int tid = threadIdx.x;
    int bn = blockIdx.y * 128;
    int wid = tid >> 6, lane = tid & 63;
    int quad = lane >> 4, l16 = lane & 15;
    int mw = (wid & 1) * 64, nw = (wid >> 1) * 64;
    f32x4 acc[4][4] = {};
    for (int k0 = 0; k0 < K; k0 += 32) {
#pragma unroll
        for (int i = 0; i < 2; ++i) {
            int c = tid + 256 * i;            // 0..511
            int row = c >> 2, ko = (c & 3) * 8;
            int ra = bm + row; if (ra >= M) ra = M - 1;
            if (AF32) {
                const float* Af = (const float*)Ap;
                float4 a0 = *(const float4*)(Af + (size_t)ra * K + k0 + ko);
                float4 a1 = *(const float4*)(Af + (size_t)ra * K + k0 + ko + 4);
                ushort4 lo, hi;
                lo.x = f2bf(a0.x); lo.y = f2bf(a0.y); lo.z = f2bf(a0.z); lo.w = f2bf(a0.w);
                hi.x = f2bf(a1.x); hi.y = f2bf(a1.y); hi.z = f2bf(a1.z); hi.w = f2bf(a1.w);
                *(ushort4*)&As[row * LDK + ko] = lo;
                *(ushort4*)&As[row * LDK + ko + 4] = hi;
            } else {
                const unsigned short* Ab = (const unsigned short*)Ap;
                uint4 va = *(const uint4*)(Ab + (size_t)ra * K + k0 + ko);
                *(uint4*)&As[row * LDK + ko] = va;
            }
            uint4 vb = *(const uint4*)(Bt + (size_t)(bn + row) * K + k0 + ko);
            *(uint4*)&Bs[row * LDK + ko] = vb;
        }
        __syncthreads();
        bf16x8 af[4], bfv[4];
#pragma unroll
        for (int i = 0; i < 4; ++i)
            af[i] = *(bf16x8*)&As[(mw + 16 * i + l16) * LDK + quad * 8];
#pragma unroll
        for (int u = 0; u < 4; ++u)
            bfv[u] = *(bf16x8*)&Bs[(nw + 16 * u + l16) * LDK + quad * 8];
#pragma unroll
        for (int i = 0; i < 4; ++i)
#pragma unroll
            for (int u = 0; u < 4; ++u)
                acc[i][u] = __builtin_amdgcn_mfma_f32_16x16x32_bf16(af[i], bfv[u], acc[i][u], 0, 0, 0);
        __syncthreads();
    }
#pragma unroll
    for (int i = 0; i < 4; ++i) {
#pragma unroll
        for (int r = 0; r < 4; ++r) {
            int grow = bm + mw + 16 * i + quad * 4 + r;
            if (grow < M) {
#pragma unroll
                for (int u = 0; u < 4; ++u) {
                    int gcol = bn + nw + 16 * u + l16;
                    C[(size_t)grow * 512 + gcol] = f2bf(acc[i][u][r]);
                }
            }
        }
    }
}

// ---------------- GATv2 gather (all types): batch-8 prefetch, no-max softmax ----------------
// Round-5 structure (known-good 88us); round-7 micro-opts: fmax-lrelu, 32-bit
// saddr-form addressing, fmaf chains. No extra VGPR arrays (round-6 lesson).
__global__ __launch_bounds__(256)
void gat_gather_all_k(Cp3 hl3, Cp3 offs3, Cp3 csr3, Cp3 att3, Cp3 bias3,
                      Vp3 out3, Int3 N3) {
    int t = blockIdx.z;
    int N = N3.a[t];
    int wave = (blockIdx.x * 256 + threadIdx.x) >> 6;
    int lane = threadIdx.x & 63;
    if (wave >= N) return;
    const char* hlB = (const char*)hl3.p[t];        // row stride 1024 B (hl||hr)
    const int* offs = (const int*)offs3.p[t];
    const int* csr = (const int*)csr3.p[t];
    const float* att = (const float*)att3.p[t];
    const float* bias = (const float*)bias3.p[t];
    unsigned short* out = (unsigned short*)out3.p[t];
    int d = wave;
    unsigned lOff = (unsigned)lane << 3;            // 8 B = 4 bf16 channels
    ushort4 hru = *(const ushort4*)(hlB + (((unsigned)d << 10) + 512u + lOff));
    float hr0 = bf2f(hru.x), hr1 = bf2f(hru.y), hr2 = bf2f(hru.z), hr3 = bf2f(hru.w);
    float4 av  = *(const float4*)(att + (lane << 2));
    float4 bv  = *(const float4*)(bias + (lane << 2));
    float l = 0.f, ac0 = 0.f, ac1 = 0.f, ac2 = 0.f, ac3 = 0.f;

    auto update = [&](ushort4 u) {
        float h0 = bf2f(u.x), h1 = bf2f(u.y), h2 = bf2f(u.z), h3 = bf2f(u.w);
        float x0 = h0 + hr0; x0 = fmaxf(x0, NEG_ATT * x0);   // exact leaky_relu
        float x1 = h1 + hr1; x1 = fmaxf(x1, NEG_ATT * x1);
        float x2 = h2 + hr2; x2 = fmaxf(x2, NEG_ATT * x2);
        float x3 = h3 + hr3; x3 = fmaxf(x3, NEG_ATT * x3);
        float part = x0 * av.x;
        part = fmaf(x1, av.y, part);
        part = fmaf(x2, av.z, part);
        part = fmaf(x3, av.w, part);
        part += __shfl_xor(part, 1);
        part += __shfl_xor(part, 2);
        part += __shfl_xor(part, 4);
        part += __shfl_xor(part, 8);        // per-head score (16-lane groups)
        float p = __expf(part);             // |score| small: shift-free softmax safe
        l += p;
        ac0 = fmaf(p, h0, ac0); ac1 = fmaf(p, h1, ac1);
        ac2 = fmaf(p, h2, ac2); ac3 = fmaf(p, h3, ac3);
    };

    update(*(const ushort4*)(hlB + (((unsigned)d << 10) + lOff)));   // self-loop

    int beg = offs[d];
    int deg = offs[d + 1] - beg;
    for (int base = 0; base < deg; base += 64) {
        int cnt = min(64, deg - base);
        int my = (base + lane < deg) ? csr[beg + base + lane] : d;
        for (int j = 0; j < cnt; j += 8) {
            int kk = min(8, cnt - j);
            ushort4 v[8];
#pragma unroll
            for (int u = 0; u < 8; ++u) {
                int s = __shfl(my, j + u);
                if (u < kk) v[u] = *(const ushort4*)(hlB + (((unsigned)s << 10) + lOff));
            }
#pragma unroll
            for (int u = 0; u < 8; ++u)
                if (u < kk) update(v[u]);
        }
    }
    float inv = 1.f / (l + 1e-16f);
    ushort4 o;
    o.x = f2bf(fmaf(ac0, inv, bv.x));
    o.y = f2bf(fmaf(ac1, inv, bv.y));
    o.z = f2bf(fmaf(ac2, inv, bv.z));
    o.w = f2bf(fmaf(ac3, inv, bv.w));
    *(ushort4*)((char*)out + (((unsigned)d << 9) + lOff)) = o;
}

// ---------------- BN stats (all types): vectorized ushort8 loads ----------------
__global__ __launch_bounds__(256)
void bn_stats_all_k(Cp3 h3, Vp3 st3, Int3 N3) {
    int t = blockIdx.y;
    const unsigned short* hp = (const unsigned short*)h3.p[t];
    float* st = (float*)st3.p[t];
    long total = (long)N3.a[t] * 256;
    int tid = threadIdx.x;
    long gt = (long)blockIdx.x * 256 + tid;
    long stride = (long)gridDim.x * 256 * 8;
    float s[8] = {0.f}, s2[8] = {0.f};
    for (long p = gt * 8; p < total; p += stride) {
        uint4 u = *(const uint4*)(hp + p);
        unsigned short* us = (unsigned short*)&u;   // 8 bf16
#pragma unroll
        for (int j = 0; j < 8; ++j) { float v = bf2f(us[j]); s[j] += v; s2[j] += v * v; }
    }
#pragma unroll
    for (int j = 0; j < 8; ++j) { s[j] += __shfl_xor(s[j], 32); s2[j] += __shfl_xor(s2[j], 32); }
    __shared__ float lds[2048];
    int wv = tid >> 6, lane = tid & 63;
    if (lane < 32) {
#pragma unroll
        for (int j = 0; j < 8; ++j) {
            lds[wv * 512 + lane * 8 + j] = s[j];
            lds[wv * 512 + 256 + lane * 8 + j] = s2[j];
        }
    }
    __syncthreads();
    for (int q = tid; q < 512; q += 256) {
        float v = lds[q] + lds[512 + q] + lds[1024 + q] + lds[1536 + q];
        atomicAdd(&st[q], v);
    }
}

// ---------------- BN apply + leaky_relu (all types), in-place bf16 ----------------
__global__ __launch_bounds__(256)
void bn_apply_all_k(Vp3 h3, Cp3 st3, const float* __restrict__ gb, const float* __restrict__ bb,
                    Int3 N3) {
    int t = blockIdx.y;
    int N = N3.a[t];
    size_t idx = (size_t)blockIdx.x * 256 + threadIdx.x;   // ushort4 index
    if (idx >= (size_t)N * 64) return;
    unsigned short* h = (unsigned short*)h3.p[t];
    const float* stats = (const float*)st3.p[t];
    const float* g = gb + (size_t)t * DFEAT;
    const float* b = bb + (size_t)t * DFEAT;
    int f4 = ((int)(idx & 63)) << 2;
    float invN = 1.f / (float)N;
    ushort4 u = ((const ushort4*)h)[idx];
    float vv[4] = {bf2f(u.x), bf2f(u.y), bf2f(u.z), bf2f(u.w)};
    ushort4 ov;
    unsigned short* op = (unsigned short*)&ov;
#pragma unroll
    for (int j = 0; j < 4; ++j) {
        int f = f4 + j;
        float mu  = stats[f] * invN;
        float var = stats[DFEAT + f] * invN - mu * mu;
        float sc  = g[f] / sqrtf(var + BN_EPS);
        float val = (vv[j] - mu) * sc + b[f];
        op[j] = f2bf(lrelu(val, NEG_ACT));
    }
    ((ushort4*)h)[idx] = ov;
}

// ---------------- fused BN + leaky_relu + classifier (all types) ----------------
__global__ __launch_bounds__(256)
void bn_cls_all_k(Cp3 R3, Cp3 st3, const float* __restrict__ gb, const float* __restrict__ bb,
                  const float* __restrict__ cW, const float* __restrict__ cb,
                  Vp3 out3, Int3 N3) {
    int t = blockIdx.y;
    int N = N3.a[t];
    int wave = (blockIdx.x * 256 + threadIdx.x) >> 6;
    int lane = threadIdx.x & 63;
    if (wave >= N) return;
    const unsigned short* R = (const unsigned short*)R3.p[t];
    const float* stats = (const float*)st3.p[t];
    const float* g = gb + (size_t)t * DFEAT;
    const float* b = bb + (size_t)t * DFEAT;
    float* out = (float*)out3.p[t];
    int f4 = lane << 2;
    float invN = 1.f / (float)N;
    ushort4 u = *(const ushort4*)(R + (size_t)wave * DFEAT + f4);
    float vv[4] = {bf2f(u.x), bf2f(u.y), bf2f(u.z), bf2f(u.w)};
    float p0 = 0.f, p1 = 0.f;
#pragma unroll
    for (int j = 0; j < 4; ++j) {
        int f = f4 + j;
        float mu  = stats[f] * invN;
        float var = stats[DFEAT + f] * invN - mu * mu;
        float sc  = g[f] / sqrtf(var + BN_EPS);
        float val = lrelu((vv[j] - mu) * sc + b[f], NEG_ACT);
        float2 w = *(const float2*)(cW + (size_t)f * 2);
        p0 += val * w.x;
        p1 += val * w.y;
    }
#pragma unroll
    for (int off = 1; off < 64; off <<= 1) {
        p0 += __shfl_xor(p0, off);
        p1 += __shfl_xor(p1, off);
    }
    if (lane == 0) {
        out[(size_t)wave * 2 + 0] = p0 + cb[0];
        out[(size_t)wave * 2 + 1] = p1 + cb[1];
    }
}

extern "C" void kernel_launch(void* const* d_in, const int* in_sizes, int n_in,
                              void* d_out, int out_size, void* d_ws, size_t ws_size,
                              hipStream_t stream) {
    const float* x0 = (const float*)d_in[0];
    const float* x1 = (const float*)d_in[1];
    const float* x2 = (const float*)d_in[2];
    const int* ei[3] = {(const int*)d_in[3], (const int*)d_in[4], (const int*)d_in[5]};
    const float* Wl1 = (const float*)d_in[6];
    const float* Wr1 = (const float*)d_in[7];
    const float* att1 = (const float*)d_in[8];
    const float* b1 = (const float*)d_in[9];
    const float* Wl2 = (const float*)d_in[10];
    const float* Wr2 = (const float*)d_in[11];
    const float* att2 = (const float*)d_in[12];
    const float* b2 = (const float*)d_in[13];
    const float* bn_g = (const float*)d_in[14];
    const float* bn_b = (const float*)d_in[15];
    const float* cW = (const float*)d_in[16];
    const float* cb = (const float*)d_in[17];

    Int3 N3, E3, nodeOff, edgeOff, bOff;
    N3.a[0] = in_sizes[0] / 128; N3.a[1] = in_sizes[1] / 128; N3.a[2] = in_sizes[2] / 128;
    E3.a[0] = in_sizes[3] / 2;   E3.a[1] = in_sizes[4] / 2;   E3.a[2] = in_sizes[5] / 2;
    int Ntot = 0, Etot = 0, btot = 0;
    int maxN = 0, maxE = 0;
    for (int i = 0; i < 3; ++i) {
        nodeOff.a[i] = Ntot; edgeOff.a[i] = Etot; bOff.a[i] = btot;
        Ntot += N3.a[i]; Etot += E3.a[i]; btot += (N3.a[i] + 255) / 256;
        if (N3.a[i] > maxN) maxN = N3.a[i];
        if (E3.a[i] > maxE) maxE = E3.a[i];
    }

    char* w = (char*)d_ws;
    auto alloc_b = [&](size_t bytes) -> void* {
        void* p = (void*)w;
        w += (bytes + 255) & ~(size_t)255;
        return p;
    };
    unsigned short* C_all  = (unsigned short*)alloc_b((size_t)Ntot * 512 * sizeof(unsigned short));
    unsigned short* Rb_all = (unsigned short*)alloc_b((size_t)Ntot * DFEAT * sizeof(unsigned short));
    unsigned short* Bt1 = (unsigned short*)alloc_b((size_t)3 * 512 * 128 * sizeof(unsigned short));
    unsigned short* Bt2 = (unsigned short*)alloc_b((size_t)3 * 512 * 256 * sizeof(unsigned short));
    int* counts_all = (int*)alloc_b((size_t)Ntot * sizeof(int));
    int* offs_all   = (int*)alloc_b((size_t)(Ntot + 3) * sizeof(int));
    int* csr_all    = (int*)alloc_b((size_t)Etot * sizeof(int));
    int* bsums_all  = (int*)alloc_b((size_t)btot * sizeof(int));
    float* stats_all = (float*)alloc_b((size_t)6 * 512 * sizeof(float));

    // per-type pointer packs
    Cp3 srcP, dstP, xP, Bt1P, Bt2P, hlP, offsP, csrP, att1P, att2P, b1P, b2P;
    Cp3 RbCP, st1CP, st2CP;
    Vp3 CP, RbP, st1P, st2P, outP;
    for (int i = 0; i < 3; ++i) {
        srcP.p[i] = ei[i];
        dstP.p[i] = ei[i] + E3.a[i];
        xP.p[i] = (i == 0) ? (const void*)x0 : (i == 1) ? (const void*)x1 : (const void*)x2;
        Bt1P.p[i] = Bt1 + (size_t)i * 512 * 128;
        Bt2P.p[i] = Bt2 + (size_t)i * 512 * 256;
        CP.p[i] = C_all + (size_t)nodeOff.a[i] * 512;
        hlP.p[i] = CP.p[i];
        RbP.p[i] = Rb_all + (size_t)nodeOff.a[i] * DFEAT;
        RbCP.p[i] = RbP.p[i];
        offsP.p[i] = offs_all + nodeOff.a[i] + i;
        csrP.p[i] = csr_all + edgeOff.a[i];
        att1P.p[i] = att1 + (size_t)i * DFEAT;
        att2P.p[i] = att2 + (size_t)i * DFEAT;
        b1P.p[i] = b1 + (size_t)i * DFEAT;
        b2P.p[i] = b2 + (size_t)i * DFEAT;
        st1P.p[i] = stats_all + (size_t)i * 512;
        st2P.p[i] = stats_all + (size_t)(3 + i) * 512;
        st1CP.p[i] = st1P.p[i];
        st2CP.p[i] = st2P.p[i];
        outP.p[i] = (float*)d_out + (size_t)nodeOff.a[i] * 2;
    }

    int maxNblk = (maxN + 255) / 256;
    int maxEblk = (maxE + 255) / 256;
    int maxMtile = (maxN + 127) / 128;
    int maxNwave = (maxN + 3) / 4;

    // one-time prep
    hipMemsetAsync(counts_all, 0, (size_t)Ntot * sizeof(int), stream);
    hipMemsetAsync(stats_all, 0, (size_t)6 * 512 * sizeof(float), stream);
    {
        int tot = 3 * 512 * 128 + 3 * 512 * 256;
        wcast_all_k<<<(tot + 255) / 256, 256, 0, stream>>>(Wl1, Wr1, Wl2, Wr2, Bt1, Bt2);
    }

    // ---- CSR build (all types) ----
    hist_all_k<<<dim3(maxEblk, 3), 256, 0, stream>>>(dstP, E3, counts_all, nodeOff);
    scan1_all_k<<<dim3(maxNblk, 3), 256, 0, stream>>>(counts_all, offs_all, bsums_all, N3, nodeOff, bOff);
    scan2_all_k<<<3, 256, 0, stream>>>(bsums_all, N3, bOff);
    scan3_all_k<<<dim3(maxNblk, 3), 256, 0, stream>>>(offs_all, counts_all, bsums_all, N3, E3, nodeOff, bOff);
    scatter_all_k<<<dim3(maxEblk, 3), 256, 0, stream>>>(srcP, dstP, E3, offs_all, counts_all, csr_all, nodeOff, edgeOff);

    // ---- layer 1 ----
    mfma_gemm_all_k<1><<<dim3(maxMtile, 4, 3), 256, 0, stream>>>(xP, Bt1P, CP, N3, 128);
    gat_gather_all_k<<<dim3(maxNwave, 1, 3), 256, 0, stream>>>(hlP, offsP, csrP, att1P, b1P, RbP, N3);
    bn_stats_all_k<<<dim3(512, 3), 256, 0, stream>>>(RbCP, st1P, N3);
    bn_apply_all_k<<<dim3(maxNwave, 3), 256, 0, stream>>>(RbP, st1CP, bn_g, bn_b, N3);

    // ---- layer 2 (A = Rb bf16, in-place BN output) ----
    mfma_gemm_all_k<0><<<dim3(maxMtile, 4, 3), 256, 0, stream>>>(RbCP, Bt2P, CP, N3, 256);
    gat_gather_all_k<<<dim3(maxNwave, 1, 3), 256, 0, stream>>>(hlP, offsP, csrP, att2P, b2P, RbP, N3);
    bn_stats_all_k<<<dim3(512, 3), 256, 0, stream>>>(RbCP, st2P, N3);

    // ---- fused BN + lrelu + classifier ----
    bn_cls_all_k<<<dim3(maxNwave, 3), 256, 0, stream>>>(RbCP, st2CP, bn_g, bn_b, cW, cb, outP, N3);
}